// Round 1
// baseline (458.245 us; speedup 1.0000x reference)
//
#include <hip/hip_runtime.h>
#include <hip/hip_bf16.h>

#define NN 50000
#define EE 800000
#define INF 128
#define HH 4
#define DD 32
#define HDIM 128   // H*D
#define OUT2 256   // fused output cols: fc (128) + res (128)

// ---------------- K0: transpose weights into wT[j][k] (k<128: fc_w, k>=128: res_w)
__global__ void transpose_w_kernel(const float* __restrict__ fc_w,
                                   const float* __restrict__ res_w,
                                   float* __restrict__ wT) {
    int idx = blockIdx.x * 256 + threadIdx.x;      // 128*256 = 32768 elements
    if (idx >= 128 * OUT2) return;
    int k = idx >> 7;          // 0..255 (output col)
    int j = idx & 127;         // input dim
    float v = (k < 128) ? fc_w[k * 128 + j] : res_w[(k - 128) * 128 + j];
    wT[j * OUT2 + k] = v;
}

// ---------------- K1: fused GEMM: h = feat @ fc_w^T (-> ws), res = feat @ res_w^T (-> out)
__global__ __launch_bounds__(256) void gemm_kernel(const float* __restrict__ feat,
                                                   const float* __restrict__ wT,
                                                   float* __restrict__ h,
                                                   float* __restrict__ out,
                                                   int n) {
    __shared__ float fs[32][128];
    int row0 = blockIdx.x * 32;
    int t = threadIdx.x;

    // stage 32x128 feat tile (float4, coalesced)
    for (int i = t; i < 32 * 32; i += 256) {
        int r = i >> 5;
        int c4 = (i & 31) << 2;
        float4 v;
        if (row0 + r < n) v = *(const float4*)&feat[(size_t)(row0 + r) * 128 + c4];
        else v = make_float4(0.f, 0.f, 0.f, 0.f);
        *(float4*)&fs[r][c4] = v;
    }
    __syncthreads();

    int tc = (t & 63) << 2;   // col0 (0..252, contiguous 4 cols)
    int tr = t >> 6;          // row base; rows tr + 4*rr
    float acc[8][4];
    #pragma unroll
    for (int rr = 0; rr < 8; ++rr)
        for (int c = 0; c < 4; ++c) acc[rr][c] = 0.f;

    #pragma unroll 4
    for (int j = 0; j < 128; ++j) {
        float4 wv = *(const float4*)&wT[j * OUT2 + tc];
        #pragma unroll
        for (int rr = 0; rr < 8; ++rr) {
            float fv = fs[tr + 4 * rr][j];
            acc[rr][0] = fmaf(fv, wv.x, acc[rr][0]);
            acc[rr][1] = fmaf(fv, wv.y, acc[rr][1]);
            acc[rr][2] = fmaf(fv, wv.z, acc[rr][2]);
            acc[rr][3] = fmaf(fv, wv.w, acc[rr][3]);
        }
    }

    #pragma unroll
    for (int rr = 0; rr < 8; ++rr) {
        int r = row0 + tr + 4 * rr;
        if (r < n) {
            if (tc < 128)
                *(float4*)&h[(size_t)r * 128 + tc] = *(float4*)&acc[rr][0];
            else
                *(float4*)&out[(size_t)r * 128 + (tc - 128)] = *(float4*)&acc[rr][0];
        }
    }
}

// ---------------- K2: el/er = einsum(h, attn_l/r) per node/head
__global__ void elr_kernel(const float* __restrict__ h,
                           const float* __restrict__ al,
                           const float* __restrict__ ar,
                           float* __restrict__ el,
                           float* __restrict__ er,
                           int n) {
    int idx = blockIdx.x * 256 + threadIdx.x;
    int node = idx >> 7;
    if (node >= n) return;
    int hd = idx & 127;
    float v = h[(size_t)node * 128 + hd];
    float a = v * al[hd];
    float b = v * ar[hd];
    // reduce over d (32 consecutive lanes)
    #pragma unroll
    for (int off = 16; off > 0; off >>= 1) {
        a += __shfl_down(a, off, 32);
        b += __shfl_down(b, off, 32);
    }
    if ((hd & 31) == 0) {
        el[node * 4 + (hd >> 5)] = a;
        er[node * 4 + (hd >> 5)] = b;
    }
}

// ---------------- K3: per-edge score: coeff = exp(leaky_relu(el[src]+er[dst])); denom += coeff
__global__ void edge_score_kernel(const int* __restrict__ src,
                                  const int* __restrict__ dst,
                                  const float* __restrict__ el,
                                  const float* __restrict__ er,
                                  float* __restrict__ coeff,
                                  float* __restrict__ denom,
                                  int e) {
    int idx = blockIdx.x * 256 + threadIdx.x;
    if (idx >= e * HH) return;
    int ed = idx >> 2;
    int hh = idx & 3;
    int s = src[ed];
    int d = dst[ed];
    float x = el[s * 4 + hh] + er[d * 4 + hh];
    x = (x > 0.f) ? x : 0.2f * x;
    float c = expf(x);
    coeff[idx] = c;
    atomicAdd(&denom[d * 4 + hh], c);
}

// ---------------- K4: aggregate: out[dst] += (coeff/denom[dst]) * h[src]
__global__ __launch_bounds__(256) void aggregate_kernel(const int* __restrict__ src,
                                                        const int* __restrict__ dst,
                                                        const float* __restrict__ h,
                                                        const float* __restrict__ coeff,
                                                        const float* __restrict__ denom,
                                                        float* __restrict__ out,
                                                        int e) {
    int idx = blockIdx.x * 256 + threadIdx.x;
    int ed = idx >> 7;
    if (ed >= e) return;
    int hd = idx & 127;
    int s = src[ed];
    int d = dst[ed];
    int hh = hd >> 5;
    float alpha = coeff[ed * 4 + hh] / denom[d * 4 + hh];
    float val = alpha * h[(size_t)s * 128 + hd];
    atomicAdd(&out[(size_t)d * 128 + hd], val);
}

extern "C" void kernel_launch(void* const* d_in, const int* in_sizes, int n_in,
                              void* d_out, int out_size, void* d_ws, size_t ws_size,
                              hipStream_t stream) {
    const float* feat   = (const float*)d_in[0];
    const int*   src    = (const int*)d_in[1];
    const int*   dst    = (const int*)d_in[2];
    const float* fc_w   = (const float*)d_in[3];
    const float* attn_l = (const float*)d_in[4];
    const float* attn_r = (const float*)d_in[5];
    const float* res_w  = (const float*)d_in[6];
    float* out = (float*)d_out;

    // workspace layout (floats)
    float* ws = (float*)d_ws;
    float* wT    = ws;                              // 128*256        = 32768
    float* h     = wT + 128 * OUT2;                 // N*128          = 6,400,000
    float* el    = h + (size_t)NN * HDIM;           // N*4
    float* er    = el + (size_t)NN * HH;            // N*4
    float* denom = er + (size_t)NN * HH;            // N*4
    float* coeff = denom + (size_t)NN * HH;         // E*4            = 3,200,000

    // K0: weight transpose
    transpose_w_kernel<<<128, 256, 0, stream>>>(fc_w, res_w, wT);

    // K1: fused double GEMM (h -> ws, residual -> out)
    int gemm_blocks = (NN + 31) / 32;
    gemm_kernel<<<gemm_blocks, 256, 0, stream>>>(feat, wT, h, out, NN);

    // K2: el/er
    elr_kernel<<<(NN * HDIM) / 256, 256, 0, stream>>>(h, attn_l, attn_r, el, er, NN);

    // zero denom
    hipMemsetAsync(denom, 0, (size_t)NN * HH * sizeof(float), stream);

    // K3: edge scores + denom
    edge_score_kernel<<<(EE * HH) / 256, 256, 0, stream>>>(src, dst, el, er, coeff, denom, EE);

    // K4: aggregation
    aggregate_kernel<<<(size_t)EE * HDIM / 256, 256, 0, stream>>>(src, dst, h, coeff, denom, out, EE);
}

// Round 2
// 424.468 us; speedup vs baseline: 1.0796x; 1.0796x over previous
//
#include <hip/hip_runtime.h>
#include <hip/hip_bf16.h>

#define NN 50000
#define EE 800000
#define HH 4
#define HDIM 128   // H*D
#define OUT2 256   // fused output cols: fc (128) + res (128)

// ---------------- K0: transpose weights into wT[j][k] (k<128: fc_w, k>=128: res_w)
__global__ void transpose_w_kernel(const float* __restrict__ fc_w,
                                   const float* __restrict__ res_w,
                                   float* __restrict__ wT) {
    int idx = blockIdx.x * 256 + threadIdx.x;      // 128*256 = 32768 elements
    if (idx >= 128 * OUT2) return;
    int k = idx >> 7;          // 0..255 (output col)
    int j = idx & 127;         // input dim
    float v = (k < 128) ? fc_w[k * 128 + j] : res_w[(k - 128) * 128 + j];
    wT[j * OUT2 + k] = v;
}

// ---------------- K1: fused GEMM: h = feat @ fc_w^T (-> ws), res = feat @ res_w^T (-> out)
__global__ __launch_bounds__(256) void gemm_kernel(const float* __restrict__ feat,
                                                   const float* __restrict__ wT,
                                                   float* __restrict__ h,
                                                   float* __restrict__ out,
                                                   int n) {
    __shared__ float fs[32][128];
    int row0 = blockIdx.x * 32;
    int t = threadIdx.x;

    for (int i = t; i < 32 * 32; i += 256) {
        int r = i >> 5;
        int c4 = (i & 31) << 2;
        float4 v;
        if (row0 + r < n) v = *(const float4*)&feat[(size_t)(row0 + r) * 128 + c4];
        else v = make_float4(0.f, 0.f, 0.f, 0.f);
        *(float4*)&fs[r][c4] = v;
    }
    __syncthreads();

    int tc = (t & 63) << 2;
    int tr = t >> 6;
    float acc[8][4];
    #pragma unroll
    for (int rr = 0; rr < 8; ++rr)
        for (int c = 0; c < 4; ++c) acc[rr][c] = 0.f;

    #pragma unroll 4
    for (int j = 0; j < 128; ++j) {
        float4 wv = *(const float4*)&wT[j * OUT2 + tc];
        #pragma unroll
        for (int rr = 0; rr < 8; ++rr) {
            float fv = fs[tr + 4 * rr][j];
            acc[rr][0] = fmaf(fv, wv.x, acc[rr][0]);
            acc[rr][1] = fmaf(fv, wv.y, acc[rr][1]);
            acc[rr][2] = fmaf(fv, wv.z, acc[rr][2]);
            acc[rr][3] = fmaf(fv, wv.w, acc[rr][3]);
        }
    }

    #pragma unroll
    for (int rr = 0; rr < 8; ++rr) {
        int r = row0 + tr + 4 * rr;
        if (r < n) {
            if (tc < 128)
                *(float4*)&h[(size_t)r * 128 + tc] = *(float4*)&acc[rr][0];
            else
                *(float4*)&out[(size_t)r * 128 + (tc - 128)] = *(float4*)&acc[rr][0];
        }
    }
}

// ---------------- K2: el/er = einsum(h, attn_l/r) per node/head
__global__ void elr_kernel(const float* __restrict__ h,
                           const float* __restrict__ al,
                           const float* __restrict__ ar,
                           float* __restrict__ el,
                           float* __restrict__ er,
                           int n) {
    int idx = blockIdx.x * 256 + threadIdx.x;
    int node = idx >> 7;
    if (node >= n) return;
    int hd = idx & 127;
    float v = h[(size_t)node * 128 + hd];
    float a = v * al[hd];
    float b = v * ar[hd];
    #pragma unroll
    for (int off = 16; off > 0; off >>= 1) {
        a += __shfl_down(a, off, 32);
        b += __shfl_down(b, off, 32);
    }
    if ((hd & 31) == 0) {
        el[node * 4 + (hd >> 5)] = a;
        er[node * 4 + (hd >> 5)] = b;
    }
}

// ---------------- K3: per-edge score: coeff = exp(leaky_relu(el[src]+er[dst]));
//                     denom += coeff; cnt[dst] += 1 (degree histogram)
__global__ void edge_score_kernel(const int* __restrict__ src,
                                  const int* __restrict__ dst,
                                  const float* __restrict__ el,
                                  const float* __restrict__ er,
                                  float* __restrict__ coeff,
                                  float* __restrict__ denom,
                                  int* __restrict__ cnt,
                                  int e) {
    int idx = blockIdx.x * 256 + threadIdx.x;
    if (idx >= e * HH) return;
    int ed = idx >> 2;
    int hh = idx & 3;
    int s = src[ed];
    int d = dst[ed];
    float x = el[s * 4 + hh] + er[d * 4 + hh];
    x = (x > 0.f) ? x : 0.2f * x;
    float c = expf(x);
    coeff[idx] = c;
    atomicAdd(&denom[d * 4 + hh], c);
    if (hh == 0) atomicAdd(&cnt[d], 1);
}

// ---------------- K4: exclusive scan over cnt -> off; cnt becomes cursor (=off)
__global__ __launch_bounds__(1024) void scan_kernel(int* __restrict__ cnt,
                                                    int* __restrict__ off,
                                                    int n) {
    __shared__ int sums[1024];
    int t = threadIdx.x;
    int chunk = (n + 1023) / 1024;
    int begin = t * chunk;
    int end = begin + chunk; if (end > n) end = n;
    int s = 0;
    for (int i = begin; i < end; ++i) s += cnt[i];
    int mysum = s;
    sums[t] = s;
    __syncthreads();
    for (int d = 1; d < 1024; d <<= 1) {
        int v = (t >= d) ? sums[t - d] : 0;
        __syncthreads();
        sums[t] += v;
        __syncthreads();
    }
    int run = sums[t] - mysum;   // exclusive prefix of this thread's chunk
    for (int i = begin; i < end; ++i) {
        int c = cnt[i];
        off[i] = run;
        cnt[i] = run;            // cursor init
        run += c;
    }
    if (t == 1023) off[n] = run;
}

// ---------------- K5: scatter edges into CSR order; record permuted src
__global__ void scatter_kernel(const int* __restrict__ src,
                               const int* __restrict__ dst,
                               int* __restrict__ cursor,
                               int* __restrict__ eidx,
                               int* __restrict__ perm_src,
                               int e) {
    int ed = blockIdx.x * 256 + threadIdx.x;
    if (ed >= e) return;
    int d = dst[ed];
    int pos = atomicAdd(&cursor[d], 1);
    eidx[pos] = ed;
    perm_src[pos] = src[ed];
}

// ---------------- K6: alpha in CSR order: alpha_perm[pos*4+h] = coeff[e*4+h]/denom[dst*4+h]
__global__ void alpha_kernel(const int* __restrict__ eidx,
                             const int* __restrict__ dst,
                             const float* __restrict__ coeff,
                             const float* __restrict__ denom,
                             float* __restrict__ alpha_perm,
                             int e) {
    int idx = blockIdx.x * 256 + threadIdx.x;
    if (idx >= e * HH) return;
    int pos = idx >> 2;
    int hh = idx & 3;
    int ed = eidx[pos];
    int d = dst[ed];
    alpha_perm[idx] = coeff[ed * 4 + hh] / denom[d * 4 + hh];
}

// ---------------- K7: gather aggregation: out[n] = residual + sum_e alpha*h[src]
__global__ __launch_bounds__(256) void gather_agg_kernel(const int* __restrict__ off,
                                                         const int* __restrict__ perm_src,
                                                         const float* __restrict__ alpha_perm,
                                                         const float* __restrict__ h,
                                                         float* __restrict__ out) {
    int t = threadIdx.x;
    int node = blockIdx.x * 2 + (t >> 7);   // 2 nodes / block, 50000 exact
    int hd = t & 127;
    int hh = hd >> 5;
    int o0 = off[node];
    int o1 = off[node + 1];
    size_t oidx = (size_t)node * 128 + hd;
    float acc = out[oidx];                  // residual already there
    int j = o0;
    for (; j + 1 < o1; j += 2) {
        int s0 = perm_src[j];
        int s1 = perm_src[j + 1];
        float a0 = alpha_perm[j * 4 + hh];
        float a1 = alpha_perm[(j + 1) * 4 + hh];
        acc = fmaf(a0, h[(size_t)s0 * 128 + hd], acc);
        acc = fmaf(a1, h[(size_t)s1 * 128 + hd], acc);
    }
    if (j < o1) {
        int s0 = perm_src[j];
        float a0 = alpha_perm[j * 4 + hh];
        acc = fmaf(a0, h[(size_t)s0 * 128 + hd], acc);
    }
    out[oidx] = acc;
}

extern "C" void kernel_launch(void* const* d_in, const int* in_sizes, int n_in,
                              void* d_out, int out_size, void* d_ws, size_t ws_size,
                              hipStream_t stream) {
    const float* feat   = (const float*)d_in[0];
    const int*   src    = (const int*)d_in[1];
    const int*   dst    = (const int*)d_in[2];
    const float* fc_w   = (const float*)d_in[3];
    const float* attn_l = (const float*)d_in[4];
    const float* attn_r = (const float*)d_in[5];
    const float* res_w  = (const float*)d_in[6];
    float* out = (float*)d_out;

    // workspace layout
    float* ws = (float*)d_ws;
    float* wT         = ws;                                  // 32768
    float* h          = wT + 128 * OUT2;                     // N*128
    float* el         = h + (size_t)NN * HDIM;               // N*4
    float* er         = el + (size_t)NN * HH;                // N*4
    float* denom      = er + (size_t)NN * HH;                // N*4
    float* coeff      = denom + (size_t)NN * HH;             // E*4
    float* alpha_perm = coeff + (size_t)EE * HH;             // E*4
    int*   cnt        = (int*)(alpha_perm + (size_t)EE * HH); // N (count -> cursor)
    int*   off        = cnt + NN;                            // N+1
    int*   eidx       = off + NN + 1;                        // E
    int*   perm_src   = eidx + EE;                           // E

    transpose_w_kernel<<<128, 256, 0, stream>>>(fc_w, res_w, wT);

    int gemm_blocks = (NN + 31) / 32;
    gemm_kernel<<<gemm_blocks, 256, 0, stream>>>(feat, wT, h, out, NN);

    elr_kernel<<<(NN * HDIM) / 256, 256, 0, stream>>>(h, attn_l, attn_r, el, er, NN);

    hipMemsetAsync(denom, 0, (size_t)NN * HH * sizeof(float), stream);
    hipMemsetAsync(cnt, 0, (size_t)NN * sizeof(int), stream);

    edge_score_kernel<<<(EE * HH) / 256, 256, 0, stream>>>(src, dst, el, er, coeff, denom, cnt, EE);

    scan_kernel<<<1, 1024, 0, stream>>>(cnt, off, NN);

    scatter_kernel<<<(EE + 255) / 256, 256, 0, stream>>>(src, dst, cnt, eidx, perm_src, EE);

    alpha_kernel<<<(EE * HH) / 256, 256, 0, stream>>>(eidx, dst, coeff, denom, alpha_perm, EE);

    gather_agg_kernel<<<NN / 2, 256, 0, stream>>>(off, perm_src, alpha_perm, h, out);
}

// Round 3
// 323.938 us; speedup vs baseline: 1.4146x; 1.3103x over previous
//
#include <hip/hip_runtime.h>
#include <hip/hip_bf16.h>

#define NN 50000
#define EE 800000
#define HH 4
#define HDIM 128   // H*D
#define OUT2 256   // fused output cols: fc (128) + res (128)

// ---------------- K0: transpose weights into wT[j][k] (k<128: fc_w, k>=128: res_w)
__global__ void transpose_w_kernel(const float* __restrict__ fc_w,
                                   const float* __restrict__ res_w,
                                   float* __restrict__ wT) {
    int idx = blockIdx.x * 256 + threadIdx.x;      // 128*256 = 32768 elements
    if (idx >= 128 * OUT2) return;
    int k = idx >> 7;          // 0..255 (output col)
    int j = idx & 127;         // input dim
    float v = (k < 128) ? fc_w[k * 128 + j] : res_w[(k - 128) * 128 + j];
    wT[j * OUT2 + k] = v;
}

// ---------------- K1: fused GEMM: h = feat @ fc_w^T (-> ws), res = feat @ res_w^T (-> out)
__global__ __launch_bounds__(256) void gemm_kernel(const float* __restrict__ feat,
                                                   const float* __restrict__ wT,
                                                   float* __restrict__ h,
                                                   float* __restrict__ out,
                                                   int n) {
    __shared__ float fs[32][128];
    int row0 = blockIdx.x * 32;
    int t = threadIdx.x;

    for (int i = t; i < 32 * 32; i += 256) {
        int r = i >> 5;
        int c4 = (i & 31) << 2;
        float4 v;
        if (row0 + r < n) v = *(const float4*)&feat[(size_t)(row0 + r) * 128 + c4];
        else v = make_float4(0.f, 0.f, 0.f, 0.f);
        *(float4*)&fs[r][c4] = v;
    }
    __syncthreads();

    int tc = (t & 63) << 2;
    int tr = t >> 6;
    float acc[8][4];
    #pragma unroll
    for (int rr = 0; rr < 8; ++rr)
        for (int c = 0; c < 4; ++c) acc[rr][c] = 0.f;

    #pragma unroll 4
    for (int j = 0; j < 128; ++j) {
        float4 wv = *(const float4*)&wT[j * OUT2 + tc];
        #pragma unroll
        for (int rr = 0; rr < 8; ++rr) {
            float fv = fs[tr + 4 * rr][j];
            acc[rr][0] = fmaf(fv, wv.x, acc[rr][0]);
            acc[rr][1] = fmaf(fv, wv.y, acc[rr][1]);
            acc[rr][2] = fmaf(fv, wv.z, acc[rr][2]);
            acc[rr][3] = fmaf(fv, wv.w, acc[rr][3]);
        }
    }

    #pragma unroll
    for (int rr = 0; rr < 8; ++rr) {
        int r = row0 + tr + 4 * rr;
        if (r < n) {
            if (tc < 128)
                *(float4*)&h[(size_t)r * 128 + tc] = *(float4*)&acc[rr][0];
            else
                *(float4*)&out[(size_t)r * 128 + (tc - 128)] = *(float4*)&acc[rr][0];
        }
    }
}

// ---------------- K2: el/er = einsum(h, attn_l/r) per node/head
__global__ void elr_kernel(const float* __restrict__ h,
                           const float* __restrict__ al,
                           const float* __restrict__ ar,
                           float* __restrict__ el,
                           float* __restrict__ er,
                           int n) {
    int idx = blockIdx.x * 256 + threadIdx.x;
    int node = idx >> 7;
    if (node >= n) return;
    int hd = idx & 127;
    float v = h[(size_t)node * 128 + hd];
    float a = v * al[hd];
    float b = v * ar[hd];
    #pragma unroll
    for (int off = 16; off > 0; off >>= 1) {
        a += __shfl_down(a, off, 32);
        b += __shfl_down(b, off, 32);
    }
    if ((hd & 31) == 0) {
        el[node * 4 + (hd >> 5)] = a;
        er[node * 4 + (hd >> 5)] = b;
    }
}

// ---------------- K3: degree histogram
__global__ void count_kernel(const int* __restrict__ dst,
                             int* __restrict__ cnt,
                             int e) {
    int ed = blockIdx.x * 256 + threadIdx.x;
    if (ed >= e) return;
    atomicAdd(&cnt[dst[ed]], 1);
}

// ---------------- K4: per-node segment base via wave prefix + one atomic per wave
__global__ void seg_alloc_kernel(const int* __restrict__ cnt,
                                 int* __restrict__ base,
                                 int* __restrict__ cursor,
                                 int* __restrict__ total,
                                 int n) {
    int idx = blockIdx.x * 256 + threadIdx.x;
    int lane = threadIdx.x & 63;
    int c = (idx < n) ? cnt[idx] : 0;
    // inclusive prefix over the 64-lane wave
    int pre = c;
    #pragma unroll
    for (int d = 1; d < 64; d <<= 1) {
        int v = __shfl_up(pre, d, 64);
        if (lane >= d) pre += v;
    }
    int wtot = __shfl(pre, 63, 64);
    int wbase = 0;
    if (lane == 63) wbase = atomicAdd(total, wtot);
    wbase = __shfl(wbase, 63, 64);
    if (idx < n) {
        int b = wbase + pre - c;   // exclusive prefix within wave + wave base
        base[idx] = b;
        cursor[idx] = b;
    }
}

// ---------------- K5: per-edge score + scatter into per-dst segment
__global__ void edge_scatter_kernel(const int* __restrict__ src,
                                    const int* __restrict__ dst,
                                    const float* __restrict__ el,
                                    const float* __restrict__ er,
                                    int* __restrict__ cursor,
                                    float* __restrict__ coeff_perm,
                                    int* __restrict__ perm_src,
                                    int e) {
    int ed = blockIdx.x * 256 + threadIdx.x;
    if (ed >= e) return;
    int s = src[ed];
    int d = dst[ed];
    float4 a = *(const float4*)&el[(size_t)s * 4];
    float4 b = *(const float4*)&er[(size_t)d * 4];
    float4 c;
    float x;
    x = a.x + b.x; x = (x > 0.f) ? x : 0.2f * x; c.x = __expf(x);
    x = a.y + b.y; x = (x > 0.f) ? x : 0.2f * x; c.y = __expf(x);
    x = a.z + b.z; x = (x > 0.f) ? x : 0.2f * x; c.z = __expf(x);
    x = a.w + b.w; x = (x > 0.f) ? x : 0.2f * x; c.w = __expf(x);
    int pos = atomicAdd(&cursor[d], 1);
    *(float4*)&coeff_perm[(size_t)pos * 4] = c;
    perm_src[pos] = s;
}

// ---------------- K6: gather aggregation: denom in-kernel, out = residual + sum alpha*h[src]
__global__ __launch_bounds__(256) void gather_agg_kernel(const int* __restrict__ base,
                                                         const int* __restrict__ cnt,
                                                         const int* __restrict__ perm_src,
                                                         const float* __restrict__ coeff_perm,
                                                         const float* __restrict__ h,
                                                         float* __restrict__ out) {
    int t = threadIdx.x;
    int node = blockIdx.x * 2 + (t >> 7);   // 2 nodes / block, 50000 exact
    int hd = t & 127;
    int hh = hd >> 5;
    int o0 = base[node];
    int deg = cnt[node];
    int o1 = o0 + deg;
    size_t oidx = (size_t)node * 128 + hd;
    float acc = out[oidx];                  // residual already there
    if (deg > 0) {
        float dnm = 0.f;
        for (int j = o0; j < o1; ++j) dnm += coeff_perm[(size_t)j * 4 + hh];
        float inv = 1.0f / dnm;
        int j = o0;
        for (; j + 1 < o1; j += 2) {
            int s0 = perm_src[j];
            int s1 = perm_src[j + 1];
            float a0 = coeff_perm[(size_t)j * 4 + hh] * inv;
            float a1 = coeff_perm[(size_t)(j + 1) * 4 + hh] * inv;
            acc = fmaf(a0, h[(size_t)s0 * 128 + hd], acc);
            acc = fmaf(a1, h[(size_t)s1 * 128 + hd], acc);
        }
        if (j < o1) {
            int s0 = perm_src[j];
            float a0 = coeff_perm[(size_t)j * 4 + hh] * inv;
            acc = fmaf(a0, h[(size_t)s0 * 128 + hd], acc);
        }
    }
    out[oidx] = acc;
}

extern "C" void kernel_launch(void* const* d_in, const int* in_sizes, int n_in,
                              void* d_out, int out_size, void* d_ws, size_t ws_size,
                              hipStream_t stream) {
    const float* feat   = (const float*)d_in[0];
    const int*   src    = (const int*)d_in[1];
    const int*   dst    = (const int*)d_in[2];
    const float* fc_w   = (const float*)d_in[3];
    const float* attn_l = (const float*)d_in[4];
    const float* attn_r = (const float*)d_in[5];
    const float* res_w  = (const float*)d_in[6];
    float* out = (float*)d_out;

    // workspace layout
    float* ws = (float*)d_ws;
    float* wT         = ws;                                   // 32768
    float* h          = wT + 128 * OUT2;                      // N*128
    float* el         = h + (size_t)NN * HDIM;                // N*4
    float* er         = el + (size_t)NN * HH;                 // N*4
    float* coeff_perm = er + (size_t)NN * HH;                 // E*4
    int*   cnt        = (int*)(coeff_perm + (size_t)EE * HH); // N
    int*   total      = cnt + NN;                             // 1  (adjacent to cnt for one memset)
    int*   base       = total + 1;                            // N
    int*   cursor     = base + NN;                            // N
    int*   perm_src   = cursor + NN;                          // E

    transpose_w_kernel<<<128, 256, 0, stream>>>(fc_w, res_w, wT);

    int gemm_blocks = (NN + 31) / 32;
    gemm_kernel<<<gemm_blocks, 256, 0, stream>>>(feat, wT, h, out, NN);

    elr_kernel<<<(NN * HDIM) / 256, 256, 0, stream>>>(h, attn_l, attn_r, el, er, NN);

    hipMemsetAsync(cnt, 0, (size_t)(NN + 1) * sizeof(int), stream);  // cnt + total

    count_kernel<<<(EE + 255) / 256, 256, 0, stream>>>(dst, cnt, EE);

    seg_alloc_kernel<<<(NN + 255) / 256, 256, 0, stream>>>(cnt, base, cursor, total, NN);

    edge_scatter_kernel<<<(EE + 255) / 256, 256, 0, stream>>>(src, dst, el, er, cursor,
                                                              coeff_perm, perm_src, EE);

    gather_agg_kernel<<<NN / 2, 256, 0, stream>>>(base, cnt, perm_src, coeff_perm, h, out);
}